// Round 1
// baseline (16.170 us; speedup 1.0000x reference)
//
#include <hip/hip_runtime.h>

#define PP 30
#define KK 17
#define PK (PP * KK)   // 510

__global__ __launch_bounds__(512) void aeloss_kernel(
    const float* __restrict__ tags,   // [B, N] (D=1, channel 0 only)
    const int*   __restrict__ kp,     // [B, P, K, 2] int32 (idx, flag)
    float*       __restrict__ out,    // [B, 2]  (push, pull)
    int N)
{
    const int b   = blockIdx.x;
    const int tid = threadIdx.x;

    __shared__ float s_sum[PP];
    __shared__ float s_cnt[PP];
    __shared__ float s_pull[PP];
    __shared__ float s_mean[PP];

    if (tid < PP) { s_sum[tid] = 0.f; s_cnt[tid] = 0.f; s_pull[tid] = 0.f; }
    __syncthreads();

    float g = 0.f, m = 0.f;
    int p = 0;
    if (tid < PK) {
        p = tid / KK;
        // (idx, flag) pair: 8-byte aligned int2 load
        const int2 kv = *reinterpret_cast<const int2*>(kp + ((size_t)b * PK + tid) * 2);
        m = (kv.y == 1) ? 1.f : 0.f;
        g = tags[(size_t)b * N + kv.x];
        atomicAdd(&s_sum[p], g * m);
        atomicAdd(&s_cnt[p], m);
    }
    __syncthreads();

    if (tid < PP) {
        s_mean[tid] = s_sum[tid] / fmaxf(s_cnt[tid], 1.f);
    }
    __syncthreads();

    if (tid < PK) {
        const float d = g - s_mean[p];
        atomicAdd(&s_pull[p], d * d * m);
    }
    __syncthreads();

    // Final reduction on the first wave (lanes 0..29 carry per-person values).
    if (tid < 64) {
        float pullp = 0.f, pv = 0.f, mean = 0.f;
        if (tid < PP) {
            const float c = s_cnt[tid];
            pv    = (c > 0.f) ? 1.f : 0.f;
            pullp = (s_pull[tid] / fmaxf(c, 1.f)) * pv;
            mean  = s_mean[tid];
        }
        // push: row-sum over pairs (tid, j>tid) of exp(-(mu_i-mu_j)^2) for valid pairs
        float row = 0.f;
        if (tid < PP && pv > 0.f) {
            #pragma unroll
            for (int j = 0; j < PP; ++j) {
                if (j > tid && s_cnt[j] > 0.f) {
                    const float d = mean - s_mean[j];
                    row += expf(-d * d);
                }
            }
        }
        // 64-lane butterfly reduce of (n, pull_sum, push_sum)
        float n = pv, pull_s = pullp, push_s = row;
        #pragma unroll
        for (int off = 32; off > 0; off >>= 1) {
            n      += __shfl_down(n,      off);
            pull_s += __shfl_down(pull_s, off);
            push_s += __shfl_down(push_s, off);
        }
        if (tid == 0) {
            const float pull   = (n > 0.f) ? (pull_s / fmaxf(n, 1.f)) : 0.f;
            const float npairs = n * (n - 1.f) * 0.5f;
            const float push   = ((n > 1.f) ? (push_s / fmaxf(npairs, 1.f)) : push_s) * 0.5f;
            out[b * 2 + 0] = push;
            out[b * 2 + 1] = pull;
        }
    }
}

extern "C" void kernel_launch(void* const* d_in, const int* in_sizes, int n_in,
                              void* d_out, int out_size, void* d_ws, size_t ws_size,
                              hipStream_t stream) {
    const float* tags = (const float*)d_in[0];
    const int*   kp   = (const int*)d_in[1];
    float*       out  = (float*)d_out;

    const int B = out_size / 2;                 // 512
    const int N = in_sizes[0] / B;              // 65536 (D=1)

    aeloss_kernel<<<B, 512, 0, stream>>>(tags, kp, out, N);
}

// Round 2
// 9.942 us; speedup vs baseline: 1.6264x; 1.6264x over previous
//
#include <hip/hip_runtime.h>

#define PP 30
#define KK 17
#define PK (PP * KK)   // 510

// One 64-lane wave per batch item. No LDS, no atomics, no barriers.
// Lane l < 60: person p = l % 30, half = l / 30 (half 0: k=0..8, half 1: k=9..16).
// Per-lane register accumulation of (sum, sumsq, cnt); halves merge via shfl_down(30);
// pull via variance decomposition; push via shfl-broadcast pair loop.
__global__ __launch_bounds__(64) void aeloss_kernel(
    const float* __restrict__ tags,   // [B, N] (D=1)
    const int*   __restrict__ kp,     // [B, P, K, 2] int32 (idx, flag)
    float*       __restrict__ out,    // [B, 2]  (push, pull)
    int N)
{
    const int b = blockIdx.x;
    const int l = threadIdx.x;                 // 0..63
    const int p    = l % PP;                   // person 0..29
    const int half = l / PP;                   // 0 or 1 (lanes >= 60 inactive)
    const bool active = (l < 2 * PP);
    const int k0 = half ? 9 : 0;
    const int kn = half ? 8 : 9;

    const int*   kpb = kp   + (size_t)b * PK * 2;
    const float* tb  = tags + (size_t)b * N;

    // Load up to 9 (idx, flag) pairs — all independent, issue together.
    int2 kv[9];
    #pragma unroll
    for (int k = 0; k < 9; ++k) {
        int kk = k0 + k; if (kk > KK - 1) kk = KK - 1;   // clamp (duplicate is masked off)
        const int pp = active ? p : 0;
        kv[k] = *reinterpret_cast<const int2*>(kpb + (pp * KK + kk) * 2);
    }
    // 9 independent gathers — full memory-level parallelism.
    float g[9];
    #pragma unroll
    for (int k = 0; k < 9; ++k) g[k] = tb[kv[k].x];

    float s = 0.f, sq = 0.f, c = 0.f;
    #pragma unroll
    for (int k = 0; k < 9; ++k) {
        const float m = (active && (k < kn) && (kv[k].y == 1)) ? 1.f : 0.f;
        s  += g[k] * m;
        sq += g[k] * g[k] * m;
        c  += m;
    }

    // Merge half 1 (lanes 30..59) into half 0 (lanes 0..29).
    s  += __shfl_down(s,  PP);
    sq += __shfl_down(sq, PP);
    c  += __shfl_down(c,  PP);

    float pv = 0.f, mean = 0.f, pullp = 0.f;
    if (l < PP) {
        pv = (c > 0.f) ? 1.f : 0.f;
        const float inv = 1.f / fmaxf(c, 1.f);
        mean  = s * inv;
        pullp = fmaxf(sq * inv - mean * mean, 0.f) * pv;   // E[x^2] - mean^2
    }

    // Push: pairs (l, j>l); broadcast person j's mean/validity from lane j.
    float row = 0.f;
    #pragma unroll
    for (int j = 1; j < PP; ++j) {
        const float meanj = __shfl(mean, j);
        const float pvj   = __shfl(pv,   j);
        const float d     = mean - meanj;
        row += (j > l) ? __expf(-d * d) * pvj * pv : 0.f;
    }

    // Butterfly reduce lanes 0..31 (lanes 30,31 carry zeros).
    float n = pv, pull_s = pullp, push_s = row;
    #pragma unroll
    for (int off = 16; off; off >>= 1) {
        n      += __shfl_down(n,      off);
        pull_s += __shfl_down(pull_s, off);
        push_s += __shfl_down(push_s, off);
    }

    if (l == 0) {
        const float pull   = (n > 0.f) ? (pull_s / fmaxf(n, 1.f)) : 0.f;
        const float npairs = n * (n - 1.f) * 0.5f;
        const float push   = ((n > 1.f) ? (push_s / fmaxf(npairs, 1.f)) : push_s) * 0.5f;
        out[b * 2 + 0] = push;
        out[b * 2 + 1] = pull;
    }
}

extern "C" void kernel_launch(void* const* d_in, const int* in_sizes, int n_in,
                              void* d_out, int out_size, void* d_ws, size_t ws_size,
                              hipStream_t stream) {
    const float* tags = (const float*)d_in[0];
    const int*   kp   = (const int*)d_in[1];
    float*       out  = (float*)d_out;

    const int B = out_size / 2;                 // 512
    const int N = in_sizes[0] / B;              // 65536 (D=1)

    aeloss_kernel<<<B, 64, 0, stream>>>(tags, kp, out, N);
}

// Round 3
// 9.878 us; speedup vs baseline: 1.6369x; 1.0065x over previous
//
#include <hip/hip_runtime.h>

#define PP 30
#define KK 17
#define PK (PP * KK)   // 510

// One 512-thread block (8 waves) per batch item; one gather per lane.
// Contributions scatter to LDS; wave 0 does a segmented per-person sum
// (stride 17 is coprime to 32 banks -> conflict-free), then the shfl-based
// push/pull finish. No atomics, one barrier.
__global__ __launch_bounds__(512) void aeloss_kernel(
    const float* __restrict__ tags,   // [B, N] (D=1)
    const int*   __restrict__ kp,     // [B, P, K, 2] int32 (idx, flag)
    float*       __restrict__ out,    // [B, 2]  (push, pull)
    int N)
{
    const int b   = blockIdx.x;
    const int tid = threadIdx.x;

    __shared__ float sA[PK];   // g*m
    __shared__ float sB[PK];   // g*g*m
    __shared__ float sC[PK];   // m

    if (tid < PK) {
        const int2 kv = *reinterpret_cast<const int2*>(kp + ((size_t)b * PK + tid) * 2);
        const float g = tags[(size_t)b * N + kv.x];
        const float m = (kv.y == 1) ? 1.f : 0.f;
        sA[tid] = g * m;
        sB[tid] = g * g * m;
        sC[tid] = m;
    }
    __syncthreads();

    if (tid < 64) {
        const int l = tid;
        float s = 0.f, sq = 0.f, c = 0.f;
        if (l < PP) {
            const int base = l * KK;
            #pragma unroll
            for (int k = 0; k < KK; ++k) {
                s  += sA[base + k];
                sq += sB[base + k];
                c  += sC[base + k];
            }
        }

        float pv = 0.f, mean = 0.f, pullp = 0.f;
        if (l < PP) {
            pv = (c > 0.f) ? 1.f : 0.f;
            const float inv = 1.f / fmaxf(c, 1.f);
            mean  = s * inv;
            pullp = fmaxf(sq * inv - mean * mean, 0.f) * pv;   // E[x^2] - mean^2
        }

        // Push: pairs (l, j>l); broadcast person j's mean/validity from lane j.
        float row = 0.f;
        #pragma unroll
        for (int j = 1; j < PP; ++j) {
            const float meanj = __shfl(mean, j);
            const float pvj   = __shfl(pv,   j);
            const float d     = mean - meanj;
            row += (j > l) ? __expf(-d * d) * pvj * pv : 0.f;
        }

        // Butterfly reduce lanes 0..31 (lanes 30,31 carry zeros).
        float n = pv, pull_s = pullp, push_s = row;
        #pragma unroll
        for (int off = 16; off; off >>= 1) {
            n      += __shfl_down(n,      off);
            pull_s += __shfl_down(pull_s, off);
            push_s += __shfl_down(push_s, off);
        }

        if (l == 0) {
            const float pull   = (n > 0.f) ? (pull_s / fmaxf(n, 1.f)) : 0.f;
            const float npairs = n * (n - 1.f) * 0.5f;
            const float push   = ((n > 1.f) ? (push_s / fmaxf(npairs, 1.f)) : push_s) * 0.5f;
            out[b * 2 + 0] = push;
            out[b * 2 + 1] = pull;
        }
    }
}

extern "C" void kernel_launch(void* const* d_in, const int* in_sizes, int n_in,
                              void* d_out, int out_size, void* d_ws, size_t ws_size,
                              hipStream_t stream) {
    const float* tags = (const float*)d_in[0];
    const int*   kp   = (const int*)d_in[1];
    float*       out  = (float*)d_out;

    const int B = out_size / 2;                 // 512
    const int N = in_sizes[0] / B;              // 65536 (D=1)

    aeloss_kernel<<<B, 512, 0, stream>>>(tags, kp, out, N);
}